// Round 14
// baseline (2551.868 us; speedup 1.0000x reference)
//
#include <hip/hip_runtime.h>
#include <stdint.h>

#define AS1 __attribute__((address_space(1)))
#define AS3 __attribute__((address_space(3)))

typedef short v8s  __attribute__((ext_vector_type(8)));
typedef float v4f  __attribute__((ext_vector_type(4)));
typedef float v16f __attribute__((ext_vector_type(16)));

#define C_IN  512
#define C_OUT 512
#define HW    64
#define COEF   1.4731391e-02f    // 1/sqrt(9*512)
#define COEF16 9.20711955e-04f   // COEF/16 (R13 fallback path)

// ---------------- new-path ws layout ----------------
// E2: [ocb16][ph32][slot9][hi2][oc32][8ic] bf16; 4608 shorts per (ocb,ph)
#define E2_BYTES   4718592u
// xt: [n8][hp66][ph32][hi2][wp66][8ic] bf16 (hp/wp = spatial+1, zero-pad border)
#define XT_SHORTS  ((size_t)8*66*66*512)
#define XT_BYTES   (XT_SHORTS*2)
// y:  [n8][oc512][i129][j132] bf16 (j 128=strip, 129..131 zero slack)
#define Y_SHORTS   ((size_t)8*512*129*132)
#define Y_BYTES    (Y_SHORTS*2)
#define WS_NEED2   ((size_t)E2_BYTES + XT_BYTES + Y_BYTES + 64)

// ---------------- R13 fallback ws layout ----------------
#define E_PH_SHORTS 9216
#define E_WS_BYTES  (2u*16u*32u*18432u)
#define WS_NEED1    ((size_t)E_WS_BYTES + XT_BYTES)

// conv2 LDS: { E 6*1024 | x [17][2hi][33]x16B } per half
#define XO2    6144
#define HALF2  24096
#define LDS2   48192
// edge sublayout: { E 9*1024 | xcol [34][2][2]x16B @9216 | xrow [2][2][33]x16B @11392 }

__device__ __forceinline__ float Gf(int i) {
    return (i < 0 || i > 3) ? 0.f : ((i == 1 || i == 2) ? 3.f : 1.f);
}
__device__ __forceinline__ short f2bf(float f) {
    uint32_t u = __float_as_uint(f);
    u += 0x7fffu + ((u >> 16) & 1u);
    return (short)(u >> 16);
}
__device__ __forceinline__ float bf2f(short s) {
    return __uint_as_float(((uint32_t)(uint16_t)s) << 16);
}
__device__ __forceinline__ uint32_t pack2bf(float a, float b) {
    return (uint32_t)(uint16_t)f2bf(a) | ((uint32_t)(uint16_t)f2bf(b) << 16);
}

// =====================================================================
// prep2: E2 image (blocks 0..1151) + x transpose (1152..5375)
// =====================================================================
__global__ __launch_bounds__(256) void prep2_kernel(const float* __restrict__ w,
                                                    const float* __restrict__ x,
                                                    short* __restrict__ e2,
                                                    short* __restrict__ xt) {
    __shared__ short tile[64][80];
    const int t = threadIdx.x;

    if (blockIdx.x < 1152) {
        // slots: 0:(1,1) 1:(1,0) 2:(1,2) 3:(0,1) 4:(2,1) 5:(0,0) 6:(0,2) 7:(2,0) 8:(2,2)
        const int PQ[9] = {4, 3, 5, 1, 7, 0, 2, 6, 8};
        int u = blockIdx.x * 256 + t;            // 294912 units of 16B
        int oc_l = u & 31;
        int hi   = (u >> 5) & 1;
        int slot = (u >> 6) % 9;
        int rest = (u >> 6) / 9;
        int ph   = rest & 31;
        int ocb  = rest >> 5;
        int pq   = PQ[slot];
        int ic0  = ph * 16 + hi * 8;
        int oc   = ocb * 32 + oc_l;
        v8s o;
        #pragma unroll
        for (int j = 0; j < 8; ++j)
            o[j] = f2bf(COEF * w[(size_t)(pq * 512 + ic0 + j) * 512 + oc]);
        *(v8s*)(e2 + (size_t)u * 8) = o;
    } else {
        const int b     = blockIdx.x - 1152;
        const int icb64 = b & 7;
        const int hp    = (b >> 3) % 66;
        const int n     = (b >> 3) / 66;
        const bool hvalid = (hp >= 1 && hp <= 64);
        if (hvalid) {
            #pragma unroll
            for (int r = 0; r < 4; ++r) {
                const int i  = (t >> 4) + r * 16;
                const int w0 = (t & 15) * 4;
                const float* src = x + ((size_t)(n * C_IN + icb64 * 64 + i) * HW + (hp - 1)) * HW + w0;
                float4 v = *(const float4*)src;
                tile[w0 + 0][i] = f2bf(v.x);
                tile[w0 + 1][i] = f2bf(v.y);
                tile[w0 + 2][i] = f2bf(v.z);
                tile[w0 + 3][i] = f2bf(v.w);
            }
        }
        __syncthreads();
        for (int u = t; u < 528; u += 256) {
            const int wp  = u >> 3;
            const int gs  = u & 7;
            const int lph = gs >> 1;
            const int hi  = gs & 1;
            v8s o = (v8s)0;
            if (hvalid && wp >= 1 && wp <= 64)
                o = *(const v8s*)&tile[wp - 1][lph * 16 + hi * 8];
            const int ph = icb64 * 4 + lph;
            *(v8s*)(xt + ((((size_t)(n * 66 + hp) * 32 + ph) * 2 + hi) * 66 + wp) * 8) = o;
        }
    }
}

// =====================================================================
// conv2: parity transposed-conv -> y.  blocks 0..2047 main, 2048..2303 edge
// A-operand = E (oc on regs), B-operand = x (spatial col on lanes)
// =====================================================================
__global__ __launch_bounds__(256, 2) void conv2_kernel(const short* __restrict__ xt,
                                                       const short* __restrict__ e2,
                                                       short* __restrict__ y) {
    __shared__ char lds_raw[LDS2];
    AS3 char* lds3 = (AS3 char*)lds_raw;

    const int tid  = threadIdx.x;
    const int lane = tid & 63;
    const int wid  = tid >> 6;
    const int l31  = lane & 31;
    const int hi   = lane >> 5;
    int bid = blockIdx.x;

    if (bid < 2048) {
        // ---------------- main blocks ----------------
        int wgid = (bid & 7) * 256 + (bid >> 3);   // n per XCD
        const int n   = wgid >> 8;
        const int r8  = wgid & 255;
        const int ocb = r8 >> 4;
        const int pa  = (r8 >> 3) & 1;             // output row parity a
        const int mb  = (r8 >> 1) & 3;
        const int vb  = r8 & 1;
        const int m0 = mb * 16, v0 = vb * 32;

        const int s0 = (pa == 0) ? 3 : 0;          // E2 slot window
        const int ns = (pa == 0) ? 6 : 3;
        const int eunits = ns * 64;
        const int units  = eunits + 1122;

        const short* ebp = e2 + (size_t)(ocb * 32) * 4608 + s0 * 512;
        const short* xbp = xt + (size_t)(n * 66 + m0) * 33792 + v0 * 8;

        const short* srcp[6]; int sdst[6], sstr[6]; bool sact[6];
        #pragma unroll
        for (int k = 0; k < 6; ++k) {
            int u = k * 256 + tid;
            sact[k] = u < units;
            if (!sact[k]) u = 0;
            if (u < eunits) { srcp[k] = ebp + u * 8; sstr[k] = 4608; sdst[k] = u * 16; }
            else {
                int j = u - eunits;
                int row = j / 66, rr = j - row * 66, h2 = rr / 33, c = rr - h2 * 33;
                srcp[k] = xbp + row * 33792 + h2 * 528 + c * 8;
                sstr[k] = 1056; sdst[k] = XO2 + j * 16;
            }
        }

#define STG2(boff, ph_) do {                                                      \
    _Pragma("unroll")                                                             \
    for (int k_ = 0; k_ < 6; ++k_)                                                \
        if (sact[k_])                                                             \
            __builtin_amdgcn_global_load_lds(                                     \
                (const AS1 void*)(srcp[k_] + (size_t)(ph_) * sstr[k_]),           \
                (AS3 void*)(lds3 + (boff) + sdst[k_]), 16, 0, 0);                 \
} while (0)

        v16f acc[4][2];
        #pragma unroll
        for (int u = 0; u < 4; ++u) { acc[u][0] = (v16f)0.f; acc[u][1] = (v16f)0.f; }

#define CMP2(boff) do {                                                           \
    v8s Ae[6];                                                                    \
    _Pragma("unroll")                                                             \
    for (int k_ = 0; k_ < 6; ++k_)                                                \
        Ae[k_] = (k_ < ns) ? *(const v8s*)(lds_raw + (boff) + k_ * 1024           \
                                           + hi * 512 + l31 * 16) : (v8s)0;       \
    v8s Bx[5][2];                                                                 \
    _Pragma("unroll")                                                             \
    for (int rr_ = 0; rr_ < 5; ++rr_)                                             \
        _Pragma("unroll")                                                         \
        for (int s_ = 0; s_ < 2; ++s_)                                            \
            Bx[rr_][s_] = *(const v8s*)(lds_raw + (boff) + XO2                    \
                + (((wid * 4 + rr_) * 2 + hi) * 33 + l31 + s_) * 16);             \
    if (pa == 0) {                                                                \
        _Pragma("unroll")                                                         \
        for (int u_ = 0; u_ < 4; ++u_) {                                          \
            acc[u_][0] = __builtin_amdgcn_mfma_f32_32x32x16_bf16(Ae[2], Bx[u_][0],     acc[u_][0], 0, 0, 0); \
            acc[u_][0] = __builtin_amdgcn_mfma_f32_32x32x16_bf16(Ae[3], Bx[u_][1],     acc[u_][0], 0, 0, 0); \
            acc[u_][0] = __builtin_amdgcn_mfma_f32_32x32x16_bf16(Ae[4], Bx[u_ + 1][0], acc[u_][0], 0, 0, 0); \
            acc[u_][0] = __builtin_amdgcn_mfma_f32_32x32x16_bf16(Ae[5], Bx[u_ + 1][1], acc[u_][0], 0, 0, 0); \
            acc[u_][1] = __builtin_amdgcn_mfma_f32_32x32x16_bf16(Ae[0], Bx[u_][1],     acc[u_][1], 0, 0, 0); \
            acc[u_][1] = __builtin_amdgcn_mfma_f32_32x32x16_bf16(Ae[1], Bx[u_ + 1][1], acc[u_][1], 0, 0, 0); \
        }                                                                         \
    } else {                                                                      \
        _Pragma("unroll")                                                         \
        for (int u_ = 0; u_ < 4; ++u_) {                                          \
            acc[u_][0] = __builtin_amdgcn_mfma_f32_32x32x16_bf16(Ae[1], Bx[u_ + 1][0], acc[u_][0], 0, 0, 0); \
            acc[u_][0] = __builtin_amdgcn_mfma_f32_32x32x16_bf16(Ae[2], Bx[u_ + 1][1], acc[u_][0], 0, 0, 0); \
            acc[u_][1] = __builtin_amdgcn_mfma_f32_32x32x16_bf16(Ae[0], Bx[u_ + 1][1], acc[u_][1], 0, 0, 0); \
        }                                                                         \
    }                                                                             \
} while (0)

        STG2(0, 0);
        __syncthreads();
        #pragma unroll 1
        for (int ph = 0; ph < 32; ++ph) {
            const int boff = (ph & 1) ? HALF2 : 0;
            const int noff = (ph & 1) ? 0 : HALF2;
            if (ph < 31) STG2(noff, ph + 1);
            CMP2(boff);
            __syncthreads();
        }
#undef STG2
#undef CMP2

        // epilogue: lanes = v (j' = 2v+b packed dword), regs = oc
        #pragma unroll
        for (int u = 0; u < 4; ++u) {
            const int i2 = 2 * (m0 + wid * 4 + u) + pa;
            #pragma unroll
            for (int r = 0; r < 16; ++r) {
                const int oc = ocb * 32 + (r & 3) + 8 * (r >> 2) + 4 * hi;
                uint32_t pk = pack2bf(acc[u][0][r], acc[u][1][r]);
                *(uint32_t*)(y + (((size_t)(n * 512 + oc) * 129 + i2) * 132 + 2 * (v0 + l31))) = pk;
            }
        }
    } else {
        // ---------------- edge blocks: y row 128, col 128, slack ----------------
        const int eb  = bid - 2048;
        const int vb  = eb & 1;
        const int ocb = (eb >> 1) & 15;
        const int n   = eb >> 5;
        const int v0  = vb * 32;

        const short* ebp = e2 + (size_t)(ocb * 32) * 4608;   // slot0
        const short* xnb = xt + (size_t)(n * 66) * 33792;

        const short* srcp[4]; int sdst[4], sstr[4]; bool sact[4];
        #pragma unroll
        for (int k = 0; k < 4; ++k) {
            int u = k * 256 + tid;
            sact[k] = u < 844;
            if (!sact[k]) u = 0;
            if (u < 576) { srcp[k] = ebp + u * 8; sstr[k] = 4608; sdst[k] = u * 16; }
            else if (u < 712) {
                int u2 = u - 576;
                int row = u2 >> 2, h2 = (u2 >> 1) & 1, c = u2 & 1;
                srcp[k] = xnb + (size_t)(v0 + row) * 33792 + h2 * 528 + (64 + c) * 8;
                sstr[k] = 1056; sdst[k] = 9216 + u2 * 16;
            } else {
                int u3 = u - 712;
                int row = u3 / 66, rr = u3 - row * 66, h2 = rr / 33, c = rr - h2 * 33;
                srcp[k] = xnb + (size_t)(64 + row) * 33792 + h2 * 528 + (v0 + c) * 8;
                sstr[k] = 1056; sdst[k] = 11392 + u3 * 16;
            }
        }

#define STGE(boff, ph_) do {                                                      \
    _Pragma("unroll")                                                             \
    for (int k_ = 0; k_ < 4; ++k_)                                                \
        if (sact[k_])                                                             \
            __builtin_amdgcn_global_load_lds(                                     \
                (const AS1 void*)(srcp[k_] + (size_t)(ph_) * sstr[k_]),           \
                (AS3 void*)(lds3 + (boff) + sdst[k_]), 16, 0, 0);                 \
} while (0)

        v16f acc0 = (v16f)0.f, acc1 = (v16f)0.f;
        const int rw3 = (l31 + 32 > 33) ? 33 : (l31 + 32);

        STGE(0, 0);
        __syncthreads();
        #pragma unroll 1
        for (int ph = 0; ph < 32; ++ph) {
            const int boff = (ph & 1) ? HALF2 : 0;
            const int noff = (ph & 1) ? 0 : HALF2;
            if (ph < 31) STGE(noff, ph + 1);
            if (wid == 0) {
                // row strip i'=128: taps (0,0),(0,2) b0 ; (0,1) b1 ; x row 63 (hp=64 -> r=0)
                v8s A5 = *(const v8s*)(lds_raw + boff + 5 * 1024 + hi * 512 + l31 * 16);
                v8s A6 = *(const v8s*)(lds_raw + boff + 6 * 1024 + hi * 512 + l31 * 16);
                v8s A3 = *(const v8s*)(lds_raw + boff + 3 * 1024 + hi * 512 + l31 * 16);
                v8s B0 = *(const v8s*)(lds_raw + boff + 11392 + ((hi) * 33 + l31) * 16);
                v8s B1 = *(const v8s*)(lds_raw + boff + 11392 + ((hi) * 33 + l31 + 1) * 16);
                acc0 = __builtin_amdgcn_mfma_f32_32x32x16_bf16(A5, B0, acc0, 0, 0, 0);
                acc0 = __builtin_amdgcn_mfma_f32_32x32x16_bf16(A6, B1, acc0, 0, 0, 0);
                acc1 = __builtin_amdgcn_mfma_f32_32x32x16_bf16(A3, B1, acc1, 0, 0, 0);
            } else if (wid == 1) {
                // col strip, even i' (a=0): taps (0,0),(2,0); lanes = m
                v8s A5 = *(const v8s*)(lds_raw + boff + 5 * 1024 + hi * 512 + l31 * 16);
                v8s A7 = *(const v8s*)(lds_raw + boff + 7 * 1024 + hi * 512 + l31 * 16);
                v8s B5 = *(const v8s*)(lds_raw + boff + 9216 + ((l31 * 2 + hi) * 2) * 16);
                v8s B7 = *(const v8s*)(lds_raw + boff + 9216 + (((l31 + 1) * 2 + hi) * 2) * 16);
                acc0 = __builtin_amdgcn_mfma_f32_32x32x16_bf16(A5, B5, acc0, 0, 0, 0);
                acc0 = __builtin_amdgcn_mfma_f32_32x32x16_bf16(A7, B7, acc0, 0, 0, 0);
            } else if (wid == 2) {
                // col strip, odd i' (a=1): tap (1,0)
                v8s A1 = *(const v8s*)(lds_raw + boff + 1 * 1024 + hi * 512 + l31 * 16);
                v8s B  = *(const v8s*)(lds_raw + boff + 9216 + (((l31 + 1) * 2 + hi) * 2) * 16);
                acc0 = __builtin_amdgcn_mfma_f32_32x32x16_bf16(A1, B, acc0, 0, 0, 0);
            } else {
                // corner y[128][128] (a=0, m=64): tap (0,0); only vb==1, lane 0 valid
                v8s A5 = *(const v8s*)(lds_raw + boff + 5 * 1024 + hi * 512 + l31 * 16);
                v8s B  = *(const v8s*)(lds_raw + boff + 9216 + ((rw3 * 2 + hi) * 2) * 16);
                acc0 = __builtin_amdgcn_mfma_f32_32x32x16_bf16(A5, B, acc0, 0, 0, 0);
            }
            __syncthreads();
        }
#undef STGE

        #pragma unroll
        for (int r = 0; r < 16; ++r) {
            const size_t ocrow = (size_t)(n * 512 + ocb * 32 + (r & 3) + 8 * (r >> 2) + 4 * hi) * 129;
            if (wid == 0) {
                *(uint32_t*)(y + (ocrow + 128) * 132 + 2 * (v0 + l31)) = pack2bf(acc0[r], acc1[r]);
            } else if (wid == 1) {
                const int i2 = 2 * (v0 + l31);
                *(uint32_t*)(y + (ocrow + i2) * 132 + 128) = pack2bf(acc0[r], 0.f);
            } else if (wid == 2) {
                const int i2 = 2 * (v0 + l31) + 1;
                *(uint32_t*)(y + (ocrow + i2) * 132 + 128) = pack2bf(acc0[r], 0.f);
            } else if (vb == 1 && l31 == 0) {
                *(uint32_t*)(y + (ocrow + 128) * 132 + 128) = pack2bf(acc0[r], 0.f);
            }
        }
        // zero slack shorts 130..131 for this block's i'-range
        const int i0  = vb ? 65 : 0;
        const int cnt = vb ? 64 : 65;
        for (int q = tid; q < cnt * 32; q += 256) {
            const int ocl = q & 31, row = q >> 5;
            *(uint32_t*)(y + (((size_t)(n * 512 + ocb * 32 + ocl) * 129 + i0 + row) * 132 + 130)) = 0u;
        }
    }
}

// =====================================================================
// blur: out[I,J] = (1/16) * sum_{a,b} v[a]v[b] * y[I+a-1, J+b-1]
// =====================================================================
__global__ __launch_bounds__(256) void blur_kernel(const short* __restrict__ y,
                                                   float* __restrict__ out) {
    __shared__ short ytile[19 * 136 + 8];
    const int bid = blockIdx.x;
    const int wg  = (bid & 7) * 4096 + (bid >> 3);   // n per XCD
    const int Ib  = wg & 7;
    const int oc  = (wg >> 3) & 511;
    const int n   = wg >> 12;
    const int I0  = Ib * 16;
    const int t   = threadIdx.x;
    const size_t ybase = (size_t)(n * 512 + oc) * 129;

    #pragma unroll
    for (int k = 0; k < 2; ++k) {
        int u = k * 256 + t;
        if (u < 323) {
            int row = u / 17, uj = u - row * 17;
            int i2  = I0 - 1 + row;
            v8s v = (v8s)0;
            if (i2 >= 0 && i2 < 129)
                v = *(const v8s*)(y + (ybase + i2) * 132 + uj * 8);
            *(v8s*)(&ytile[row * 136 + uj * 8]) = v;
        }
    }
    if (t == 0) *(v8s*)(&ytile[19 * 136]) = (v8s)0;
    __syncthreads();

    const int tj = t & 31, ti = t >> 5;
    float* ob = out + (size_t)(n * 512 + oc) * 128 * 128;
    #pragma unroll
    for (int rr = 0; rr < 2; ++rr) {
        const int Il = ti + rr * 8;
        float s0 = 0.f, s1 = 0.f, s2 = 0.f, s3 = 0.f;
        #pragma unroll
        for (int a = 0; a < 4; ++a) {
            const float va = (a == 1 || a == 2) ? 3.f : 1.f;
            float f[7];
            #pragma unroll
            for (int p = 0; p < 7; ++p) {
                int jj = tj * 4 + p - 1;
                int idx = (jj < 0) ? 19 * 136 : (Il + a) * 136 + jj;
                f[p] = bf2f(ytile[idx]);
            }
            s0 += va * (f[0] + 3.f * f[1] + 3.f * f[2] + f[3]);
            s1 += va * (f[1] + 3.f * f[2] + 3.f * f[3] + f[4]);
            s2 += va * (f[2] + 3.f * f[3] + 3.f * f[4] + f[5]);
            s3 += va * (f[3] + 3.f * f[4] + 3.f * f[5] + f[6]);
        }
        v4f o;
        o[0] = s0 * 0.0625f; o[1] = s1 * 0.0625f; o[2] = s2 * 0.0625f; o[3] = s3 * 0.0625f;
        *(v4f*)(ob + (size_t)(I0 + Il) * 128 + tj * 4) = o;
    }
}

// =====================================================================
// ---------------- R13 fallback path (validated) ----------------------
// =====================================================================
__global__ __launch_bounds__(256) void prep_kernel(const float* __restrict__ w,
                                                   const float* __restrict__ x,
                                                   short* __restrict__ ews,
                                                   short* __restrict__ xt) {
    __shared__ short tile[64][80];
    const int t = threadIdx.x;
    if (blockIdx.x < 4608) {
        int u = blockIdx.x * 256 + t;
        int oc_l = u & 31;
        int hi   = (u >> 5) & 1;
        int tap  = (u >> 6) % 18;
        int rest = (u >> 6) / 18;
        int ph   = rest & 31;
        int ocb  = (rest >> 5) & 15;
        int pu   = rest >> 9;
        int pv   = tap & 1;
        int ts   = tap >> 1;
        int tt   = ts / 3, ss = ts - tt * 3;
        int m    = 2 * tt + 1 - pu;
        int nn   = 2 * ss + 1 - pv;
        int ic0  = ph * 16 + hi * 8;
        int oc   = ocb * 32 + oc_l;
        v8s o;
        #pragma unroll
        for (int j = 0; j < 8; ++j) {
            float acc = 0.f;
            #pragma unroll
            for (int p = 0; p < 3; ++p) {
                float gm = Gf(m - p);
                if (gm != 0.f) {
                    #pragma unroll
                    for (int q = 0; q < 3; ++q) {
                        float gn = Gf(nn - q);
                        if (gn != 0.f)
                            acc += gm * gn * w[((size_t)(p * 3 + q) * C_IN + ic0 + j) * C_OUT + oc];
                    }
                }
            }
            o[j] = f2bf(acc * COEF16);
        }
        *(v8s*)(ews + (size_t)u * 8) = o;
    } else {
        const int b     = blockIdx.x - 4608;
        const int icb64 = b & 7;
        const int hp    = (b >> 3) % 66;
        const int n     = (b >> 3) / 66;
        const bool hvalid = (hp >= 1 && hp <= 64);
        if (hvalid) {
            #pragma unroll
            for (int r = 0; r < 4; ++r) {
                const int i  = (t >> 4) + r * 16;
                const int w0 = (t & 15) * 4;
                const float* src = x + ((size_t)(n * C_IN + icb64 * 64 + i) * HW + (hp - 1)) * HW + w0;
                float4 v = *(const float4*)src;
                tile[w0 + 0][i] = f2bf(v.x);
                tile[w0 + 1][i] = f2bf(v.y);
                tile[w0 + 2][i] = f2bf(v.z);
                tile[w0 + 3][i] = f2bf(v.w);
            }
        }
        __syncthreads();
        for (int u = t; u < 528; u += 256) {
            const int wp  = u >> 3;
            const int gs  = u & 7;
            const int lph = gs >> 1;
            const int hi  = gs & 1;
            v8s o = (v8s)0;
            if (hvalid && wp >= 1 && wp <= 64)
                o = *(const v8s*)&tile[wp - 1][lph * 16 + hi * 8];
            const int ph = icb64 * 4 + lph;
            *(v8s*)(xt + ((((size_t)(n * 66 + hp) * 32 + ph) * 2 + hi) * 66 + wp) * 8) = o;
        }
    }
}

#define XOFF1 18432
#define HALF1 38016
__global__ __launch_bounds__(256, 2) void conv_mfma_kernel(const short* __restrict__ xt,
                                                           const short* __restrict__ ews,
                                                           float* __restrict__ out) {
    int bid  = blockIdx.x;
    int wgid = (bid & 7) * 256 + (bid >> 3);
    const int n   = wgid >> 8;
    const int r8  = wgid & 255;
    const int ocb = r8 >> 4;
    const int pu  = (r8 >> 3) & 1;
    const int uhb = (r8 >> 1) & 3;
    const int vhb = r8 & 1;
    const int uh0 = uhb * 16, vh0 = vhb * 32;

    __shared__ char lds_raw[2 * HALF1];
    AS3 char* lds3 = (AS3 char*)lds_raw;

    const int tid  = threadIdx.x;
    const int lane = tid & 63;
    const int wid  = tid >> 6;
    const int l31  = lane & 31;
    const int hi   = lane >> 5;

    const short* ebase = ews + (size_t)((pu * 16 + ocb) * 32) * E_PH_SHORTS + (size_t)tid * 8;
    const short* xbase = xt + (size_t)(n * 66 + uh0) * 33792 + vh0 * 8;
    int xoff[6], xdst[6];
    #pragma unroll
    for (int k = 0; k < 6; ++k) {
        int j;
        if (k == 0)      j = tid - 128;
        else if (k == 5) j = 1152 + tid;
        else             j = 128 + (k - 1) * 256 + tid;
        if (j < 0 || j >= 1224) j = 0;
        const int r  = j / 68;
        const int rr = j - r * 68;
        const int h_ = rr / 34;
        const int c_ = rr - h_ * 34;
        xoff[k] = r * 33792 + h_ * 528 + c_ * 8;
        xdst[k] = XOFF1 + j * 16;
    }

#define STAGE1(bufoff, ph_) do {                                                      \
    const short* ep_ = ebase + (size_t)(ph_) * E_PH_SHORTS;                           \
    const short* xp_ = xbase + (size_t)(ph_) * 1056;                                  \
    _Pragma("unroll")                                                                 \
    for (int it_ = 0; it_ < 4; ++it_)                                                 \
        __builtin_amdgcn_global_load_lds((const AS1 void*)(ep_ + it_ * 2048),         \
            (AS3 void*)(lds3 + (bufoff) + it_ * 4096 + tid * 16), 16, 0, 0);          \
    if (tid < 128)                                                                    \
        __builtin_amdgcn_global_load_lds((const AS1 void*)(ep_ + 8192),               \
            (AS3 void*)(lds3 + (bufoff) + 16384 + tid * 16), 16, 0, 0);               \
    else                                                                              \
        __builtin_amdgcn_global_load_lds((const AS1 void*)(xp_ + xoff[0]),            \
            (AS3 void*)(lds3 + (bufoff) + xdst[0]), 16, 0, 0);                        \
    _Pragma("unroll")                                                                 \
    for (int k_ = 1; k_ < 5; ++k_)                                                    \
        __builtin_amdgcn_global_load_lds((const AS1 void*)(xp_ + xoff[k_]),           \
            (AS3 void*)(lds3 + (bufoff) + xdst[k_]), 16, 0, 0);                       \
    if (tid < 72)                                                                     \
        __builtin_amdgcn_global_load_lds((const AS1 void*)(xp_ + xoff[5]),            \
            (AS3 void*)(lds3 + (bufoff) + xdst[5]), 16, 0, 0);                        \
} while (0)

    v16f acc[4][2];
    #pragma unroll
    for (int u = 0; u < 4; ++u) { acc[u][0] = (v16f)0.f; acc[u][1] = (v16f)0.f; }

#define COMPUTE1(bufoff) do {                                                         \
    _Pragma("unroll")                                                                 \
    for (int s_ = 0; s_ < 3; ++s_) {                                                  \
        const int c_ = l31 + s_;                                                      \
        v8s A_[6];                                                                    \
        _Pragma("unroll")                                                             \
        for (int rr_ = 0; rr_ < 6; ++rr_)                                             \
            A_[rr_] = *(const v8s*)(lds_raw + (bufoff) + XOFF1                        \
                     + (((wid * 4 + rr_) * 2 + hi) * 34 + c_) * 16);                  \
        _Pragma("unroll")                                                             \
        for (int t_ = 0; t_ < 3; ++t_) {                                              \
            _Pragma("unroll")                                                         \
            for (int pv_ = 0; pv_ < 2; ++pv_) {                                       \
                v8s B_ = *(const v8s*)(lds_raw + (bufoff)                             \
                         + ((((t_ * 3 + s_) * 2 + pv_) * 2 + hi) * 32 + l31) * 16);   \
                _Pragma("unroll")                                                     \
                for (int u_ = 0; u_ < 4; ++u_)                                        \
                    acc[u_][pv_] = __builtin_amdgcn_mfma_f32_32x32x16_bf16(           \
                                       A_[u_ + t_], B_, acc[u_][pv_], 0, 0, 0);       \
            }                                                                         \
        }                                                                             \
    }                                                                                 \
} while (0)

    STAGE1(0, 0);
    __syncthreads();
    #pragma unroll 1
    for (int ph = 0; ph < 32; ++ph) {
        const int boff = (ph & 1) ? HALF1 : 0;
        const int noff = (ph & 1) ? 0 : HALF1;
        if (ph < 31) STAGE1(noff, ph + 1);
        COMPUTE1(boff);
        __syncthreads();
    }
#undef STAGE1
#undef COMPUTE1

    const int oc_g = ocb * 32 + l31;
    float* ob = out + ((size_t)(n * C_OUT + oc_g)) * 128 * 128;
    #pragma unroll
    for (int u = 0; u < 4; ++u) {
        const int h = 2 * (uh0 + wid * 4 + u) + pu;
        #pragma unroll
        for (int g = 0; g < 4; ++g) {
            const int rb    = g * 4;
            const int vh_lb = 8 * g + 4 * hi;
            float f8[8];
            #pragma unroll
            for (int i = 0; i < 4; ++i) {
                f8[2 * i]     = acc[u][0][rb + i];
                f8[2 * i + 1] = acc[u][1][rb + i];
            }
            float* dst = ob + (size_t)h * 128 + 2 * (vh0 + vh_lb);
            *(v4f*)dst       = *(v4f*)&f8[0];
            *(v4f*)(dst + 4) = *(v4f*)&f8[4];
        }
    }
}

// ---------------- round-1 VALU fallback ----------------
#define ICB 8
#define UB  4
__global__ __launch_bounds__(256) void conv_par_kernel(
        const float* __restrict__ x, const float* __restrict__ w,
        float* __restrict__ out) {
    const int octile = blockIdx.x;
    const int n      = blockIdx.y >> 4;
    const int uhb    = blockIdx.y & 15;
    const int pu     = blockIdx.z >> 1;
    const int pv     = blockIdx.z & 1;
    const int t    = threadIdx.x;
    const int lane = t & 63;
    const int wg   = t >> 6;
    const int ocb  = octile * 64;
    const int uh0  = uhb * UB;
    __shared__ float xs[ICB][6][66];
    __shared__ float esw[9][ICB][64];
    float acc[UB][16];
    #pragma unroll
    for (int u = 0; u < UB; ++u)
        #pragma unroll
        for (int i = 0; i < 16; ++i) acc[u][i] = 0.f;
    for (int icb = 0; icb < C_IN; icb += ICB) {
        __syncthreads();
        for (int e = t; e < ICB * 6 * 66; e += 256) {
            int col = e % 66; int tmp = e / 66; int row = tmp % 6; int ic = tmp / 6;
            int h = uh0 - 1 + row; int ww = col - 1;
            float v = 0.f;
            if (h >= 0 && h < HW && ww >= 0 && ww < HW)
                v = x[((n * C_IN + icb + ic) * HW + h) * HW + ww];
            xs[ic][row][col] = v;
        }
        for (int e = t; e < 9 * ICB * 64; e += 256) {
            int oc = e & 63; int ic = (e >> 6) & (ICB - 1); int pq = e >> 9;
            esw[pq][ic][oc] = w[(pq * C_IN + icb + ic) * C_OUT + ocb + oc];
        }
        __syncthreads();
        float ereg[18];
        #pragma unroll
        for (int j = 0; j < 18; ++j) {
            int e = t + j * 256; int oc = e & 63; int ic = (e >> 6) & (ICB - 1);
            int tap = e >> 9; int t3 = tap / 3, s3 = tap - t3 * 3;
            int m = 2 * t3 + 1 - pu; int nn = 2 * s3 + 1 - pv;
            float gm0 = Gf(m), gm1 = Gf(m - 1), gm2 = Gf(m - 2);
            float gn0 = Gf(nn), gn1 = Gf(nn - 1), gn2 = Gf(nn - 2);
            float s =
              gm0 * (gn0 * esw[0][ic][oc] + gn1 * esw[1][ic][oc] + gn2 * esw[2][ic][oc])
            + gm1 * (gn0 * esw[3][ic][oc] + gn1 * esw[4][ic][oc] + gn2 * esw[5][ic][oc])
            + gm2 * (gn0 * esw[6][ic][oc] + gn1 * esw[7][ic][oc] + gn2 * esw[8][ic][oc]);
            ereg[j] = s * COEF16;
        }
        __syncthreads();
        #pragma unroll
        for (int j = 0; j < 18; ++j) {
            int e = t + j * 256; int oc = e & 63; int ic = (e >> 6) & (ICB - 1);
            int tap = e >> 9;
            esw[tap][ic][oc] = ereg[j];
        }
        __syncthreads();
        for (int ic = 0; ic < ICB; ++ic) {
            #pragma unroll
            for (int t3 = 0; t3 < 3; ++t3) {
                #pragma unroll
                for (int s3 = 0; s3 < 3; ++s3) {
                    const int tap = t3 * 3 + s3;
                    float ev[16];
                    #pragma unroll
                    for (int r = 0; r < 4; ++r)
                        *(float4*)&ev[r * 4] = *(const float4*)&esw[tap][ic][wg * 16 + r * 4];
                    float xv[UB];
                    #pragma unroll
                    for (int u = 0; u < UB; ++u) xv[u] = xs[ic][u + t3][lane + s3];
                    #pragma unroll
                    for (int u = 0; u < UB; ++u)
                        #pragma unroll
                        for (int i = 0; i < 16; ++i) acc[u][i] += xv[u] * ev[i];
                }
            }
        }
    }
    #pragma unroll
    for (int u = 0; u < UB; ++u) {
        int urow = 2 * (uh0 + u) + pu;
        #pragma unroll
        for (int i = 0; i < 16; ++i) {
            int oc = ocb + wg * 16 + i;
            out[((n * C_OUT + oc) * 128 + urow) * 128 + 2 * lane + pv] = acc[u][i];
        }
    }
}

extern "C" void kernel_launch(void* const* d_in, const int* in_sizes, int n_in,
                              void* d_out, int out_size, void* d_ws, size_t ws_size,
                              hipStream_t stream) {
    const float* x = (const float*)d_in[0];   // (8,512,64,64) fp32
    const float* w = (const float*)d_in[1];   // (3,3,512,512) fp32 HWIO
    float* out = (float*)d_out;               // (8,512,128,128) fp32

    if (ws_size >= WS_NEED2) {
        short* e2  = (short*)d_ws;
        short* xtp = (short*)((char*)d_ws + E2_BYTES);
        short* y   = (short*)((char*)d_ws + E2_BYTES + XT_BYTES);
        prep2_kernel<<<5376, 256, 0, stream>>>(w, x, e2, xtp);
        conv2_kernel<<<2304, 256, 0, stream>>>(xtp, e2, y);
        blur_kernel<<<32768, 256, 0, stream>>>(y, out);
    } else if (ws_size >= WS_NEED1) {
        short* ews = (short*)d_ws;
        short* xtp = (short*)((char*)d_ws + E_WS_BYTES);
        prep_kernel<<<8832, 256, 0, stream>>>(w, x, ews, xtp);
        conv_mfma_kernel<<<2048, 256, 0, stream>>>(xtp, ews, out);
    } else {
        dim3 grid(8, 128, 4);
        conv_par_kernel<<<grid, 256, 0, stream>>>(x, w, out);
    }
}

// Round 15
// 315.483 us; speedup vs baseline: 8.0888x; 8.0888x over previous
//
#include <hip/hip_runtime.h>
#include <stdint.h>

#define AS1 __attribute__((address_space(1)))
#define AS3 __attribute__((address_space(3)))

typedef short v8s  __attribute__((ext_vector_type(8)));
typedef float v4f  __attribute__((ext_vector_type(4)));
typedef float v16f __attribute__((ext_vector_type(16)));

#define C_IN  512
#define C_OUT 512
#define HW    64
#define COEF   1.4731391e-02f    // 1/sqrt(9*512)
#define COEF16 9.20711955e-04f   // COEF/16 (R13 fallback path)

// ---------------- new-path ws layout ----------------
// E2: [ocb16][ph32][slot9][hi2][oc32][8ic] bf16; 4608 shorts per (ocb,ph)
#define E2_BYTES   4718592u
// xt: [n8][hp66][ph32][hi2][wp66][8ic] bf16 (hp/wp = spatial+1, zero-pad border)
#define XT_SHORTS  ((size_t)8*66*66*512)
#define XT_BYTES   (XT_SHORTS*2)
// y:  [n8][oc512][i129][j132] bf16 (j 128=strip, 129..131 zero slack)
#define Y_SHORTS   ((size_t)8*512*129*132)
#define Y_BYTES    (Y_SHORTS*2)
#define WS_NEED2   ((size_t)E2_BYTES + XT_BYTES + Y_BYTES + 64)

// ---------------- R13 fallback ws layout ----------------
#define E_PH_SHORTS 9216
#define E_WS_BYTES  (2u*16u*32u*18432u)
#define WS_NEED1    ((size_t)E_WS_BYTES + XT_BYTES)

// edge LDS half: { E 9*1024 | xcol [34][2][2]x16B @9216 | xrow [2][2][33]x16B @11392 } = 13504
#define HALFE  13504

__device__ __forceinline__ float Gf(int i) {
    return (i < 0 || i > 3) ? 0.f : ((i == 1 || i == 2) ? 3.f : 1.f);
}
__device__ __forceinline__ short f2bf(float f) {
    uint32_t u = __float_as_uint(f);
    u += 0x7fffu + ((u >> 16) & 1u);
    return (short)(u >> 16);
}
__device__ __forceinline__ float bf2f(short s) {
    return __uint_as_float(((uint32_t)(uint16_t)s) << 16);
}
__device__ __forceinline__ uint32_t pack2bf(float a, float b) {
    return (uint32_t)(uint16_t)f2bf(a) | ((uint32_t)(uint16_t)f2bf(b) << 16);
}

// =====================================================================
// prep2: E2 image (blocks 0..1151) + x transpose (1152..5375)
// =====================================================================
__global__ __launch_bounds__(256) void prep2_kernel(const float* __restrict__ w,
                                                    const float* __restrict__ x,
                                                    short* __restrict__ e2,
                                                    short* __restrict__ xt) {
    __shared__ short tile[64][80];
    const int t = threadIdx.x;

    if (blockIdx.x < 1152) {
        // slots: 0:(1,1) 1:(1,0) 2:(1,2) 3:(0,1) 4:(2,1) 5:(0,0) 6:(0,2) 7:(2,0) 8:(2,2)
        const int PQ[9] = {4, 3, 5, 1, 7, 0, 2, 6, 8};
        int u = blockIdx.x * 256 + t;            // 294912 units of 16B
        int oc_l = u & 31;
        int hi   = (u >> 5) & 1;
        int slot = (u >> 6) % 9;
        int rest = (u >> 6) / 9;
        int ph   = rest & 31;
        int ocb  = rest >> 5;
        int pq   = PQ[slot];
        int ic0  = ph * 16 + hi * 8;
        int oc   = ocb * 32 + oc_l;
        v8s o;
        #pragma unroll
        for (int j = 0; j < 8; ++j)
            o[j] = f2bf(COEF * w[(size_t)(pq * 512 + ic0 + j) * 512 + oc]);
        *(v8s*)(e2 + (size_t)u * 8) = o;
    } else {
        const int b     = blockIdx.x - 1152;
        const int icb64 = b & 7;
        const int hp    = (b >> 3) % 66;
        const int n     = (b >> 3) / 66;
        const bool hvalid = (hp >= 1 && hp <= 64);
        if (hvalid) {
            #pragma unroll
            for (int r = 0; r < 4; ++r) {
                const int i  = (t >> 4) + r * 16;
                const int w0 = (t & 15) * 4;
                const float* src = x + ((size_t)(n * C_IN + icb64 * 64 + i) * HW + (hp - 1)) * HW + w0;
                float4 v = *(const float4*)src;
                tile[w0 + 0][i] = f2bf(v.x);
                tile[w0 + 1][i] = f2bf(v.y);
                tile[w0 + 2][i] = f2bf(v.z);
                tile[w0 + 3][i] = f2bf(v.w);
            }
        }
        __syncthreads();
        for (int u = t; u < 528; u += 256) {
            const int wp  = u >> 3;
            const int gs  = u & 7;
            const int lph = gs >> 1;
            const int hi  = gs & 1;
            v8s o = (v8s)0;
            if (hvalid && wp >= 1 && wp <= 64)
                o = *(const v8s*)&tile[wp - 1][lph * 16 + hi * 8];
            const int ph = icb64 * 4 + lph;
            *(v8s*)(xt + ((((size_t)(n * 66 + hp) * 32 + ph) * 2 + hi) * 66 + wp) * 8) = o;
        }
    }
}

// =====================================================================
// conv2_main<PA>: parity transposed-conv -> y (interior), spill-safe
// =====================================================================
template<int PA>
__global__ __launch_bounds__(256, 2) void conv2_main_kernel(const short* __restrict__ xt,
                                                            const short* __restrict__ e2,
                                                            short* __restrict__ y) {
    constexpr int NS = (PA == 0) ? 6 : 3;
    constexpr int XO = NS * 64 * 16;       // x section LDS byte offset
    constexpr int HF = XO + 17952;
    __shared__ char lds_raw[2 * HF];
    AS3 char* lds3 = (AS3 char*)lds_raw;

    int bid  = blockIdx.x;
    int wgid = (bid & 7) * 128 + (bid >> 3);   // 1024 blocks, n per XCD
    const int n   = wgid >> 7;
    const int r7  = wgid & 127;
    const int ocb = r7 >> 3;
    const int mb  = (r7 >> 1) & 3;
    const int vb  = r7 & 1;
    const int m0 = mb * 16, v0 = vb * 32;

    const int tid  = threadIdx.x;
    const int lane = tid & 63;
    const int wid  = tid >> 6;
    const int l31  = lane & 31;
    const int hi   = lane >> 5;

    const short* ebase = e2 + (size_t)(ocb * 32) * 4608 + (PA == 0 ? 1536 : 0);
    const short* xbase = xt + (size_t)(n * 66 + m0) * 33792 + v0 * 8;

    // x 16B-units j2 in [0,1122): row=j2/66, h2=(j2%66)/33, c=(j2%66)%33
    int xo[5];
    #pragma unroll
    for (int k = 0; k < 5; ++k) {
        int j2 = k * 256 + tid;
        if (j2 >= 1122) j2 = 0;
        const int row = j2 / 66, rr = j2 - row * 66;
        const int h2 = rr / 33, c = rr - h2 * 33;
        xo[k] = row * 33792 + h2 * 528 + c * 8;
    }

#define STG(boff, ph_) do {                                                       \
    const short* xp_ = xbase + (size_t)(ph_) * 1056;                              \
    const short* ep_ = ebase + (size_t)(ph_) * 4608;                              \
    _Pragma("unroll")                                                             \
    for (int k_ = 0; k_ < 4; ++k_)                                                \
        __builtin_amdgcn_global_load_lds((const AS1 void*)(xp_ + xo[k_]),         \
            (AS3 void*)(lds3 + (boff) + XO + (k_ * 256 + tid) * 16), 16, 0, 0);   \
    if (tid < 98)                                                                 \
        __builtin_amdgcn_global_load_lds((const AS1 void*)(xp_ + xo[4]),          \
            (AS3 void*)(lds3 + (boff) + XO + (1024 + tid) * 16), 16, 0, 0);       \
    if (PA == 0) {                                                                \
        __builtin_amdgcn_global_load_lds((const AS1 void*)(ep_ + tid * 8),        \
            (AS3 void*)(lds3 + (boff) + tid * 16), 16, 0, 0);                     \
        if (tid < 128)                                                            \
            __builtin_amdgcn_global_load_lds((const AS1 void*)(ep_ + 2048 + tid * 8), \
                (AS3 void*)(lds3 + (boff) + 4096 + tid * 16), 16, 0, 0);          \
    } else {                                                                      \
        if (tid < 192)                                                            \
            __builtin_amdgcn_global_load_lds((const AS1 void*)(ep_ + tid * 8),    \
                (AS3 void*)(lds3 + (boff) + tid * 16), 16, 0, 0);                 \
    }                                                                             \
} while (0)

    v16f acc[4][2];
    #pragma unroll
    for (int u = 0; u < 4; ++u) { acc[u][0] = (v16f)0.f; acc[u][1] = (v16f)0.f; }

#define CMP(boff) do {                                                            \
    v8s Ae[NS];                                                                   \
    _Pragma("unroll")                                                             \
    for (int k_ = 0; k_ < NS; ++k_)                                               \
        Ae[k_] = *(const v8s*)(lds_raw + (boff) + k_ * 1024 + hi * 512 + l31 * 16); \
    v8s Bx[5][2];                                                                 \
    _Pragma("unroll")                                                             \
    for (int rr_ = 0; rr_ < 5; ++rr_)                                             \
        _Pragma("unroll")                                                         \
        for (int s_ = 0; s_ < 2; ++s_)                                            \
            Bx[rr_][s_] = *(const v8s*)(lds_raw + (boff) + XO                     \
                + (((wid * 4 + rr_) * 2 + hi) * 33 + l31 + s_) * 16);             \
    if constexpr (PA == 0) {                                                      \
        _Pragma("unroll")                                                         \
        for (int u_ = 0; u_ < 4; ++u_) {                                          \
            acc[u_][0] = __builtin_amdgcn_mfma_f32_32x32x16_bf16(Ae[2], Bx[u_][0],     acc[u_][0], 0, 0, 0); \
            acc[u_][0] = __builtin_amdgcn_mfma_f32_32x32x16_bf16(Ae[3], Bx[u_][1],     acc[u_][0], 0, 0, 0); \
            acc[u_][0] = __builtin_amdgcn_mfma_f32_32x32x16_bf16(Ae[4], Bx[u_ + 1][0], acc[u_][0], 0, 0, 0); \
            acc[u_][0] = __builtin_amdgcn_mfma_f32_32x32x16_bf16(Ae[5], Bx[u_ + 1][1], acc[u_][0], 0, 0, 0); \
            acc[u_][1] = __builtin_amdgcn_mfma_f32_32x32x16_bf16(Ae[0], Bx[u_][1],     acc[u_][1], 0, 0, 0); \
            acc[u_][1] = __builtin_amdgcn_mfma_f32_32x32x16_bf16(Ae[1], Bx[u_ + 1][1], acc[u_][1], 0, 0, 0); \
        }                                                                         \
    } else {                                                                      \
        _Pragma("unroll")                                                         \
        for (int u_ = 0; u_ < 4; ++u_) {                                          \
            acc[u_][0] = __builtin_amdgcn_mfma_f32_32x32x16_bf16(Ae[1], Bx[u_ + 1][0], acc[u_][0], 0, 0, 0); \
            acc[u_][0] = __builtin_amdgcn_mfma_f32_32x32x16_bf16(Ae[2], Bx[u_ + 1][1], acc[u_][0], 0, 0, 0); \
            acc[u_][1] = __builtin_amdgcn_mfma_f32_32x32x16_bf16(Ae[0], Bx[u_ + 1][1], acc[u_][1], 0, 0, 0); \
        }                                                                         \
    }                                                                             \
} while (0)

    STG(0, 0);
    __syncthreads();
    #pragma unroll 1
    for (int ph = 0; ph < 32; ++ph) {
        const int boff = (ph & 1) ? HF : 0;
        const int noff = (ph & 1) ? 0 : HF;
        if (ph < 31) STG(noff, ph + 1);
        CMP(boff);
        __syncthreads();
    }
#undef STG
#undef CMP

    // epilogue: lanes = v (j' = 2v+b packed dword), regs = oc
    #pragma unroll
    for (int u = 0; u < 4; ++u) {
        const int i2 = 2 * (m0 + wid * 4 + u) + PA;
        #pragma unroll
        for (int r = 0; r < 16; ++r) {
            const int oc = ocb * 32 + (r & 3) + 8 * (r >> 2) + 4 * hi;
            uint32_t pk = pack2bf(acc[u][0][r], acc[u][1][r]);
            *(uint32_t*)(y + (((size_t)(n * 512 + oc) * 129 + i2) * 132 + 2 * (v0 + l31))) = pk;
        }
    }
}

// =====================================================================
// conv2_edge: y row 128, col 128, corner, slack zeros
// =====================================================================
__global__ __launch_bounds__(256, 2) void conv2_edge_kernel(const short* __restrict__ xt,
                                                            const short* __restrict__ e2,
                                                            short* __restrict__ y) {
    __shared__ char lds_raw[2 * HALFE];
    AS3 char* lds3 = (AS3 char*)lds_raw;

    const int tid  = threadIdx.x;
    const int lane = tid & 63;
    const int wid  = tid >> 6;
    const int l31  = lane & 31;
    const int hi   = lane >> 5;

    const int eb  = blockIdx.x;
    const int vb  = eb & 1;
    const int ocb = (eb >> 1) & 15;
    const int n   = eb >> 5;
    const int v0  = vb * 32;

    const short* ebp = e2 + (size_t)(ocb * 32) * 4608;   // slot0
    const short* xnb = xt + (size_t)(n * 66) * 33792;

    const short* srcp[4]; int sdst[4], sstr[4]; bool sact[4];
    #pragma unroll
    for (int k = 0; k < 4; ++k) {
        int u = k * 256 + tid;
        sact[k] = u < 844;
        if (!sact[k]) u = 0;
        if (u < 576) { srcp[k] = ebp + u * 8; sstr[k] = 4608; sdst[k] = u * 16; }
        else if (u < 712) {
            int u2 = u - 576;
            int row = u2 >> 2, h2 = (u2 >> 1) & 1, c = u2 & 1;
            srcp[k] = xnb + (size_t)(v0 + row) * 33792 + h2 * 528 + (64 + c) * 8;
            sstr[k] = 1056; sdst[k] = 9216 + u2 * 16;
        } else {
            int u3 = u - 712;
            int row = u3 / 66, rr = u3 - row * 66, h2 = rr / 33, c = rr - h2 * 33;
            srcp[k] = xnb + (size_t)(64 + row) * 33792 + h2 * 528 + (v0 + c) * 8;
            sstr[k] = 1056; sdst[k] = 11392 + u3 * 16;
        }
    }

#define STGE(boff, ph_) do {                                                      \
    _Pragma("unroll")                                                             \
    for (int k_ = 0; k_ < 4; ++k_)                                                \
        if (sact[k_])                                                             \
            __builtin_amdgcn_global_load_lds(                                     \
                (const AS1 void*)(srcp[k_] + (size_t)(ph_) * sstr[k_]),           \
                (AS3 void*)(lds3 + (boff) + sdst[k_]), 16, 0, 0);                 \
} while (0)

    v16f acc0 = (v16f)0.f, acc1 = (v16f)0.f;
    const int rw3 = (l31 + 32 > 33) ? 33 : (l31 + 32);

    STGE(0, 0);
    __syncthreads();
    #pragma unroll 1
    for (int ph = 0; ph < 32; ++ph) {
        const int boff = (ph & 1) ? HALFE : 0;
        const int noff = (ph & 1) ? 0 : HALFE;
        if (ph < 31) STGE(noff, ph + 1);
        if (wid == 0) {
            v8s A5 = *(const v8s*)(lds_raw + boff + 5 * 1024 + hi * 512 + l31 * 16);
            v8s A6 = *(const v8s*)(lds_raw + boff + 6 * 1024 + hi * 512 + l31 * 16);
            v8s A3 = *(const v8s*)(lds_raw + boff + 3 * 1024 + hi * 512 + l31 * 16);
            v8s B0 = *(const v8s*)(lds_raw + boff + 11392 + ((hi) * 33 + l31) * 16);
            v8s B1 = *(const v8s*)(lds_raw + boff + 11392 + ((hi) * 33 + l31 + 1) * 16);
            acc0 = __builtin_amdgcn_mfma_f32_32x32x16_bf16(A5, B0, acc0, 0, 0, 0);
            acc0 = __builtin_amdgcn_mfma_f32_32x32x16_bf16(A6, B1, acc0, 0, 0, 0);
            acc1 = __builtin_amdgcn_mfma_f32_32x32x16_bf16(A3, B1, acc1, 0, 0, 0);
        } else if (wid == 1) {
            v8s A5 = *(const v8s*)(lds_raw + boff + 5 * 1024 + hi * 512 + l31 * 16);
            v8s A7 = *(const v8s*)(lds_raw + boff + 7 * 1024 + hi * 512 + l31 * 16);
            v8s B5 = *(const v8s*)(lds_raw + boff + 9216 + ((l31 * 2 + hi) * 2) * 16);
            v8s B7 = *(const v8s*)(lds_raw + boff + 9216 + (((l31 + 1) * 2 + hi) * 2) * 16);
            acc0 = __builtin_amdgcn_mfma_f32_32x32x16_bf16(A5, B5, acc0, 0, 0, 0);
            acc0 = __builtin_amdgcn_mfma_f32_32x32x16_bf16(A7, B7, acc0, 0, 0, 0);
        } else if (wid == 2) {
            v8s A1 = *(const v8s*)(lds_raw + boff + 1 * 1024 + hi * 512 + l31 * 16);
            v8s B  = *(const v8s*)(lds_raw + boff + 9216 + (((l31 + 1) * 2 + hi) * 2) * 16);
            acc0 = __builtin_amdgcn_mfma_f32_32x32x16_bf16(A1, B, acc0, 0, 0, 0);
        } else {
            v8s A5 = *(const v8s*)(lds_raw + boff + 5 * 1024 + hi * 512 + l31 * 16);
            v8s B  = *(const v8s*)(lds_raw + boff + 9216 + ((rw3 * 2 + hi) * 2) * 16);
            acc0 = __builtin_amdgcn_mfma_f32_32x32x16_bf16(A5, B, acc0, 0, 0, 0);
        }
        __syncthreads();
    }
#undef STGE

    #pragma unroll
    for (int r = 0; r < 16; ++r) {
        const size_t ocrow = (size_t)(n * 512 + ocb * 32 + (r & 3) + 8 * (r >> 2) + 4 * hi) * 129;
        if (wid == 0) {
            *(uint32_t*)(y + (ocrow + 128) * 132 + 2 * (v0 + l31)) = pack2bf(acc0[r], acc1[r]);
        } else if (wid == 1) {
            const int i2 = 2 * (v0 + l31);
            *(uint32_t*)(y + (ocrow + i2) * 132 + 128) = pack2bf(acc0[r], 0.f);
        } else if (wid == 2) {
            const int i2 = 2 * (v0 + l31) + 1;
            *(uint32_t*)(y + (ocrow + i2) * 132 + 128) = pack2bf(acc0[r], 0.f);
        } else if (vb == 1 && l31 == 0) {
            *(uint32_t*)(y + (ocrow + 128) * 132 + 128) = pack2bf(acc0[r], 0.f);
        }
    }
    // zero slack shorts 130..131 for this block's i'-range
    const int i0  = vb ? 65 : 0;
    const int cnt = vb ? 64 : 65;
    for (int q = tid; q < cnt * 32; q += 256) {
        const int ocl = q & 31, row = q >> 5;
        *(uint32_t*)(y + (((size_t)(n * 512 + ocb * 32 + ocl) * 129 + i0 + row) * 132 + 130)) = 0u;
    }
}

// =====================================================================
// blur: out[I,J] = (1/16) * sum_{a,b} v[a]v[b] * y[I+a-1, J+b-1]
// =====================================================================
__global__ __launch_bounds__(256) void blur_kernel(const short* __restrict__ y,
                                                   float* __restrict__ out) {
    __shared__ short ytile[19 * 136 + 8];
    const int bid = blockIdx.x;
    const int wg  = (bid & 7) * 4096 + (bid >> 3);   // n per XCD
    const int Ib  = wg & 7;
    const int oc  = (wg >> 3) & 511;
    const int n   = wg >> 12;
    const int I0  = Ib * 16;
    const int t   = threadIdx.x;
    const size_t ybase = (size_t)(n * 512 + oc) * 129;

    #pragma unroll
    for (int k = 0; k < 2; ++k) {
        int u = k * 256 + t;
        if (u < 323) {
            int row = u / 17, uj = u - row * 17;
            int i2  = I0 - 1 + row;
            v8s v = (v8s)0;
            if (i2 >= 0 && i2 < 129)
                v = *(const v8s*)(y + (ybase + i2) * 132 + uj * 8);
            *(v8s*)(&ytile[row * 136 + uj * 8]) = v;
        }
    }
    if (t == 0) *(v8s*)(&ytile[19 * 136]) = (v8s)0;
    __syncthreads();

    const int tj = t & 31, ti = t >> 5;
    float* ob = out + (size_t)(n * 512 + oc) * 128 * 128;
    #pragma unroll
    for (int rr = 0; rr < 2; ++rr) {
        const int Il = ti + rr * 8;
        float s0 = 0.f, s1 = 0.f, s2 = 0.f, s3 = 0.f;
        #pragma unroll
        for (int a = 0; a < 4; ++a) {
            const float va = (a == 1 || a == 2) ? 3.f : 1.f;
            float f[7];
            #pragma unroll
            for (int p = 0; p < 7; ++p) {
                int jj = tj * 4 + p - 1;
                int idx = (jj < 0) ? 19 * 136 : (Il + a) * 136 + jj;
                f[p] = bf2f(ytile[idx]);
            }
            s0 += va * (f[0] + 3.f * f[1] + 3.f * f[2] + f[3]);
            s1 += va * (f[1] + 3.f * f[2] + 3.f * f[3] + f[4]);
            s2 += va * (f[2] + 3.f * f[3] + 3.f * f[4] + f[5]);
            s3 += va * (f[3] + 3.f * f[4] + 3.f * f[5] + f[6]);
        }
        v4f o;
        o[0] = s0 * 0.0625f; o[1] = s1 * 0.0625f; o[2] = s2 * 0.0625f; o[3] = s3 * 0.0625f;
        *(v4f*)(ob + (size_t)(I0 + Il) * 128 + tj * 4) = o;
    }
}

// =====================================================================
// ---------------- R13 fallback path (validated) ----------------------
// =====================================================================
__global__ __launch_bounds__(256) void prep_kernel(const float* __restrict__ w,
                                                   const float* __restrict__ x,
                                                   short* __restrict__ ews,
                                                   short* __restrict__ xt) {
    __shared__ short tile[64][80];
    const int t = threadIdx.x;
    if (blockIdx.x < 4608) {
        int u = blockIdx.x * 256 + t;
        int oc_l = u & 31;
        int hi   = (u >> 5) & 1;
        int tap  = (u >> 6) % 18;
        int rest = (u >> 6) / 18;
        int ph   = rest & 31;
        int ocb  = (rest >> 5) & 15;
        int pu   = rest >> 9;
        int pv   = tap & 1;
        int ts   = tap >> 1;
        int tt   = ts / 3, ss = ts - tt * 3;
        int m    = 2 * tt + 1 - pu;
        int nn   = 2 * ss + 1 - pv;
        int ic0  = ph * 16 + hi * 8;
        int oc   = ocb * 32 + oc_l;
        v8s o;
        #pragma unroll
        for (int j = 0; j < 8; ++j) {
            float acc = 0.f;
            #pragma unroll
            for (int p = 0; p < 3; ++p) {
                float gm = Gf(m - p);
                if (gm != 0.f) {
                    #pragma unroll
                    for (int q = 0; q < 3; ++q) {
                        float gn = Gf(nn - q);
                        if (gn != 0.f)
                            acc += gm * gn * w[((size_t)(p * 3 + q) * C_IN + ic0 + j) * C_OUT + oc];
                    }
                }
            }
            o[j] = f2bf(acc * COEF16);
        }
        *(v8s*)(ews + (size_t)u * 8) = o;
    } else {
        const int b     = blockIdx.x - 4608;
        const int icb64 = b & 7;
        const int hp    = (b >> 3) % 66;
        const int n     = (b >> 3) / 66;
        const bool hvalid = (hp >= 1 && hp <= 64);
        if (hvalid) {
            #pragma unroll
            for (int r = 0; r < 4; ++r) {
                const int i  = (t >> 4) + r * 16;
                const int w0 = (t & 15) * 4;
                const float* src = x + ((size_t)(n * C_IN + icb64 * 64 + i) * HW + (hp - 1)) * HW + w0;
                float4 v = *(const float4*)src;
                tile[w0 + 0][i] = f2bf(v.x);
                tile[w0 + 1][i] = f2bf(v.y);
                tile[w0 + 2][i] = f2bf(v.z);
                tile[w0 + 3][i] = f2bf(v.w);
            }
        }
        __syncthreads();
        for (int u = t; u < 528; u += 256) {
            const int wp  = u >> 3;
            const int gs  = u & 7;
            const int lph = gs >> 1;
            const int hi  = gs & 1;
            v8s o = (v8s)0;
            if (hvalid && wp >= 1 && wp <= 64)
                o = *(const v8s*)&tile[wp - 1][lph * 16 + hi * 8];
            const int ph = icb64 * 4 + lph;
            *(v8s*)(xt + ((((size_t)(n * 66 + hp) * 32 + ph) * 2 + hi) * 66 + wp) * 8) = o;
        }
    }
}

#define XOFF1 18432
#define HALF1 38016
__global__ __launch_bounds__(256, 2) void conv_mfma_kernel(const short* __restrict__ xt,
                                                           const short* __restrict__ ews,
                                                           float* __restrict__ out) {
    int bid  = blockIdx.x;
    int wgid = (bid & 7) * 256 + (bid >> 3);
    const int n   = wgid >> 8;
    const int r8  = wgid & 255;
    const int ocb = r8 >> 4;
    const int pu  = (r8 >> 3) & 1;
    const int uhb = (r8 >> 1) & 3;
    const int vhb = r8 & 1;
    const int uh0 = uhb * 16, vh0 = vhb * 32;

    __shared__ char lds_raw[2 * HALF1];
    AS3 char* lds3 = (AS3 char*)lds_raw;

    const int tid  = threadIdx.x;
    const int lane = tid & 63;
    const int wid  = tid >> 6;
    const int l31  = lane & 31;
    const int hi   = lane >> 5;

    const short* ebase = ews + (size_t)((pu * 16 + ocb) * 32) * E_PH_SHORTS + (size_t)tid * 8;
    const short* xbase = xt + (size_t)(n * 66 + uh0) * 33792 + vh0 * 8;
    int xoff[6], xdst[6];
    #pragma unroll
    for (int k = 0; k < 6; ++k) {
        int j;
        if (k == 0)      j = tid - 128;
        else if (k == 5) j = 1152 + tid;
        else             j = 128 + (k - 1) * 256 + tid;
        if (j < 0 || j >= 1224) j = 0;
        const int r  = j / 68;
        const int rr = j - r * 68;
        const int h_ = rr / 34;
        const int c_ = rr - h_ * 34;
        xoff[k] = r * 33792 + h_ * 528 + c_ * 8;
        xdst[k] = XOFF1 + j * 16;
    }

#define STAGE1(bufoff, ph_) do {                                                      \
    const short* ep_ = ebase + (size_t)(ph_) * E_PH_SHORTS;                           \
    const short* xp_ = xbase + (size_t)(ph_) * 1056;                                  \
    _Pragma("unroll")                                                                 \
    for (int it_ = 0; it_ < 4; ++it_)                                                 \
        __builtin_amdgcn_global_load_lds((const AS1 void*)(ep_ + it_ * 2048),         \
            (AS3 void*)(lds3 + (bufoff) + it_ * 4096 + tid * 16), 16, 0, 0);          \
    if (tid < 128)                                                                    \
        __builtin_amdgcn_global_load_lds((const AS1 void*)(ep_ + 8192),               \
            (AS3 void*)(lds3 + (bufoff) + 16384 + tid * 16), 16, 0, 0);               \
    else                                                                              \
        __builtin_amdgcn_global_load_lds((const AS1 void*)(xp_ + xoff[0]),            \
            (AS3 void*)(lds3 + (bufoff) + xdst[0]), 16, 0, 0);                        \
    _Pragma("unroll")                                                                 \
    for (int k_ = 1; k_ < 5; ++k_)                                                    \
        __builtin_amdgcn_global_load_lds((const AS1 void*)(xp_ + xoff[k_]),           \
            (AS3 void*)(lds3 + (bufoff) + xdst[k_]), 16, 0, 0);                       \
    if (tid < 72)                                                                     \
        __builtin_amdgcn_global_load_lds((const AS1 void*)(xp_ + xoff[5]),            \
            (AS3 void*)(lds3 + (bufoff) + xdst[5]), 16, 0, 0);                        \
} while (0)

    v16f acc[4][2];
    #pragma unroll
    for (int u = 0; u < 4; ++u) { acc[u][0] = (v16f)0.f; acc[u][1] = (v16f)0.f; }

#define COMPUTE1(bufoff) do {                                                         \
    _Pragma("unroll")                                                                 \
    for (int s_ = 0; s_ < 3; ++s_) {                                                  \
        const int c_ = l31 + s_;                                                      \
        v8s A_[6];                                                                    \
        _Pragma("unroll")                                                             \
        for (int rr_ = 0; rr_ < 6; ++rr_)                                             \
            A_[rr_] = *(const v8s*)(lds_raw + (bufoff) + XOFF1                        \
                     + (((wid * 4 + rr_) * 2 + hi) * 34 + c_) * 16);                  \
        _Pragma("unroll")                                                             \
        for (int t_ = 0; t_ < 3; ++t_) {                                              \
            _Pragma("unroll")                                                         \
            for (int pv_ = 0; pv_ < 2; ++pv_) {                                       \
                v8s B_ = *(const v8s*)(lds_raw + (bufoff)                             \
                         + ((((t_ * 3 + s_) * 2 + pv_) * 2 + hi) * 32 + l31) * 16);   \
                _Pragma("unroll")                                                     \
                for (int u_ = 0; u_ < 4; ++u_)                                        \
                    acc[u_][pv_] = __builtin_amdgcn_mfma_f32_32x32x16_bf16(           \
                                       A_[u_ + t_], B_, acc[u_][pv_], 0, 0, 0);       \
            }                                                                         \
        }                                                                             \
    }                                                                                 \
} while (0)

    STAGE1(0, 0);
    __syncthreads();
    #pragma unroll 1
    for (int ph = 0; ph < 32; ++ph) {
        const int boff = (ph & 1) ? HALF1 : 0;
        const int noff = (ph & 1) ? 0 : HALF1;
        if (ph < 31) STAGE1(noff, ph + 1);
        COMPUTE1(boff);
        __syncthreads();
    }
#undef STAGE1
#undef COMPUTE1

    const int oc_g = ocb * 32 + l31;
    float* ob = out + ((size_t)(n * C_OUT + oc_g)) * 128 * 128;
    #pragma unroll
    for (int u = 0; u < 4; ++u) {
        const int h = 2 * (uh0 + wid * 4 + u) + pu;
        #pragma unroll
        for (int g = 0; g < 4; ++g) {
            const int rb    = g * 4;
            const int vh_lb = 8 * g + 4 * hi;
            float f8[8];
            #pragma unroll
            for (int i = 0; i < 4; ++i) {
                f8[2 * i]     = acc[u][0][rb + i];
                f8[2 * i + 1] = acc[u][1][rb + i];
            }
            float* dst = ob + (size_t)h * 128 + 2 * (vh0 + vh_lb);
            *(v4f*)dst       = *(v4f*)&f8[0];
            *(v4f*)(dst + 4) = *(v4f*)&f8[4];
        }
    }
}

// ---------------- round-1 VALU fallback ----------------
#define ICB 8
#define UB  4
__global__ __launch_bounds__(256) void conv_par_kernel(
        const float* __restrict__ x, const float* __restrict__ w,
        float* __restrict__ out) {
    const int octile = blockIdx.x;
    const int n      = blockIdx.y >> 4;
    const int uhb    = blockIdx.y & 15;
    const int pu     = blockIdx.z >> 1;
    const int pv     = blockIdx.z & 1;
    const int t    = threadIdx.x;
    const int lane = t & 63;
    const int wg   = t >> 6;
    const int ocb  = octile * 64;
    const int uh0  = uhb * UB;
    __shared__ float xs[ICB][6][66];
    __shared__ float esw[9][ICB][64];
    float acc[UB][16];
    #pragma unroll
    for (int u = 0; u < UB; ++u)
        #pragma unroll
        for (int i = 0; i < 16; ++i) acc[u][i] = 0.f;
    for (int icb = 0; icb < C_IN; icb += ICB) {
        __syncthreads();
        for (int e = t; e < ICB * 6 * 66; e += 256) {
            int col = e % 66; int tmp = e / 66; int row = tmp % 6; int ic = tmp / 6;
            int h = uh0 - 1 + row; int ww = col - 1;
            float v = 0.f;
            if (h >= 0 && h < HW && ww >= 0 && ww < HW)
                v = x[((n * C_IN + icb + ic) * HW + h) * HW + ww];
            xs[ic][row][col] = v;
        }
        for (int e = t; e < 9 * ICB * 64; e += 256) {
            int oc = e & 63; int ic = (e >> 6) & (ICB - 1); int pq = e >> 9;
            esw[pq][ic][oc] = w[(pq * C_IN + icb + ic) * C_OUT + ocb + oc];
        }
        __syncthreads();
        float ereg[18];
        #pragma unroll
        for (int j = 0; j < 18; ++j) {
            int e = t + j * 256; int oc = e & 63; int ic = (e >> 6) & (ICB - 1);
            int tap = e >> 9; int t3 = tap / 3, s3 = tap - t3 * 3;
            int m = 2 * t3 + 1 - pu; int nn = 2 * s3 + 1 - pv;
            float gm0 = Gf(m), gm1 = Gf(m - 1), gm2 = Gf(m - 2);
            float gn0 = Gf(nn), gn1 = Gf(nn - 1), gn2 = Gf(nn - 2);
            float s =
              gm0 * (gn0 * esw[0][ic][oc] + gn1 * esw[1][ic][oc] + gn2 * esw[2][ic][oc])
            + gm1 * (gn0 * esw[3][ic][oc] + gn1 * esw[4][ic][oc] + gn2 * esw[5][ic][oc])
            + gm2 * (gn0 * esw[6][ic][oc] + gn1 * esw[7][ic][oc] + gn2 * esw[8][ic][oc]);
            ereg[j] = s * COEF16;
        }
        __syncthreads();
        #pragma unroll
        for (int j = 0; j < 18; ++j) {
            int e = t + j * 256; int oc = e & 63; int ic = (e >> 6) & (ICB - 1);
            int tap = e >> 9;
            esw[tap][ic][oc] = ereg[j];
        }
        __syncthreads();
        for (int ic = 0; ic < ICB; ++ic) {
            #pragma unroll
            for (int t3 = 0; t3 < 3; ++t3) {
                #pragma unroll
                for (int s3 = 0; s3 < 3; ++s3) {
                    const int tap = t3 * 3 + s3;
                    float ev[16];
                    #pragma unroll
                    for (int r = 0; r < 4; ++r)
                        *(float4*)&ev[r * 4] = *(const float4*)&esw[tap][ic][wg * 16 + r * 4];
                    float xv[UB];
                    #pragma unroll
                    for (int u = 0; u < UB; ++u) xv[u] = xs[ic][u + t3][lane + s3];
                    #pragma unroll
                    for (int u = 0; u < UB; ++u)
                        #pragma unroll
                        for (int i = 0; i < 16; ++i) acc[u][i] += xv[u] * ev[i];
                }
            }
        }
    }
    #pragma unroll
    for (int u = 0; u < UB; ++u) {
        int urow = 2 * (uh0 + u) + pu;
        #pragma unroll
        for (int i = 0; i < 16; ++i) {
            int oc = ocb + wg * 16 + i;
            out[((n * C_OUT + oc) * 128 + urow) * 128 + 2 * lane + pv] = acc[u][i];
        }
    }
}

extern "C" void kernel_launch(void* const* d_in, const int* in_sizes, int n_in,
                              void* d_out, int out_size, void* d_ws, size_t ws_size,
                              hipStream_t stream) {
    const float* x = (const float*)d_in[0];   // (8,512,64,64) fp32
    const float* w = (const float*)d_in[1];   // (3,3,512,512) fp32 HWIO
    float* out = (float*)d_out;               // (8,512,128,128) fp32

    if (ws_size >= WS_NEED2) {
        short* e2  = (short*)d_ws;
        short* xtp = (short*)((char*)d_ws + E2_BYTES);
        short* y   = (short*)((char*)d_ws + E2_BYTES + XT_BYTES);
        prep2_kernel<<<5376, 256, 0, stream>>>(w, x, e2, xtp);
        conv2_main_kernel<0><<<1024, 256, 0, stream>>>(xtp, e2, y);
        conv2_main_kernel<1><<<1024, 256, 0, stream>>>(xtp, e2, y);
        conv2_edge_kernel<<<256, 256, 0, stream>>>(xtp, e2, y);
        blur_kernel<<<32768, 256, 0, stream>>>(y, out);
    } else if (ws_size >= WS_NEED1) {
        short* ews = (short*)d_ws;
        short* xtp = (short*)((char*)d_ws + E_WS_BYTES);
        prep_kernel<<<8832, 256, 0, stream>>>(w, x, ews, xtp);
        conv_mfma_kernel<<<2048, 256, 0, stream>>>(xtp, ews, out);
    } else {
        dim3 grid(8, 128, 4);
        conv_par_kernel<<<grid, 256, 0, stream>>>(x, w, out);
    }
}